// Round 2
// baseline (181.153 us; speedup 1.0000x reference)
//
#include <hip/hip_runtime.h>
#include <hip/hip_bf16.h>

#define B_DIM 4
#define C_DIM 192
#define T_SEQ 2048
#define H_DIM 2
#define K_DIM 96
#define BAND 256
#define IT 16            // q rows per attn block
#define NJT 34           // j-tiles of 16 in window (544 slots)
#define PBS 552          // prob row stride in shorts (16B-aligned, 20-bank offset/row)
#define HSH (16*PBS)     // shorts per head's prob block
#define PMW 17           // packed-mask words per row
#define XSTR 200         // proj LDS row stride in shorts (400B: 16B-aligned, 4-bank skew)
#define OSTR 200         // out-tile row stride in shorts
#define PDS 40           // pd row stride in shorts

typedef __attribute__((ext_vector_type(8))) short bf16x8;
typedef __attribute__((ext_vector_type(4))) short bf16x4;
typedef __attribute__((ext_vector_type(4))) float f32x4;
#define MFMA16 __builtin_amdgcn_mfma_f32_16x16x32_bf16

__device__ __forceinline__ float bfbits2f(short s) {
    union { short s; __hip_bfloat16 h; } u; u.s = s; return __bfloat162float(u.h);
}
__device__ __forceinline__ short f2bf_bits(float f) {
    union { __hip_bfloat16 h; short s; } u; u.h = __float2bfloat16(f); return u.s;
}

// ---- workspace layout (bytes) ----
// WqT|WkT|WvT|WoT bf16 [192][192] (WqT prescaled); bqs fp32[192];
// relkbf bf16[16][96] (rows 9..15 zero); rvt bf16[96][32] (relv^T, cols 9..31 zero);
// qbf,kbf bf16 [bh][t][96]; vtb bf16 [bh][96][t]
#define OFF_WT(m)  ((size_t)(m)*73728)
#define OFF_BQS    ((size_t)294912)
#define OFF_RELKBF ((size_t)295680)
#define OFF_RVT    ((size_t)298752)
#define OFF_QBF    ((size_t)304896)
#define OFF_KBF    (OFF_QBF + 3145728)
#define OFF_VTB    (OFF_KBF + 3145728)

// ---------------------------------------------------------------------------
// Prep: [0,576) weight transpose; 576: scaled bias + rel-k + relv^T tables.
// ---------------------------------------------------------------------------
__global__ __launch_bounds__(256)
void prep_kernel(const float* __restrict__ Wq, const float* __restrict__ Wk,
                 const float* __restrict__ Wv, const float* __restrict__ Wo,
                 const float* __restrict__ bq, const float* __restrict__ relk,
                 const float* __restrict__ relv, char* __restrict__ ws)
{
    const float qscale = 0.10206207261596577f;   // 1/sqrt(96)
    const int bidx = blockIdx.x;
    const int tid  = threadIdx.x;

    if (bidx < 576) {                       // ---- weight transpose
        const size_t idx = (size_t)bidx*256 + tid;
        const int mi  = (int)(idx / 36864);
        const int rem = (int)(idx % 36864);
        const int c = rem / C_DIM, d = rem % C_DIM;
        const float* src = (mi == 0) ? Wq : (mi == 1) ? Wk : (mi == 2) ? Wv : Wo;
        float v = src[c*C_DIM + d];
        if (mi == 0) v *= qscale;
        ((short*)(ws + OFF_WT(mi)))[d*C_DIM + c] = f2bf_bits(v);
        return;
    }
    if (tid < C_DIM)
        ((float*)(ws + OFF_BQS))[tid] = bq[tid]*qscale;
    short* rkb = (short*)(ws + OFF_RELKBF);
    for (int idx = tid; idx < 16*K_DIM; idx += 256) {
        const int row = idx / K_DIM;
        rkb[idx] = (row < 9) ? f2bf_bits(relk[idx]) : (short)0;
    }
    short* rvt = (short*)(ws + OFF_RVT);
    for (int idx = tid; idx < K_DIM*32; idx += 256) {
        const int col = idx >> 5, dd = idx & 31;
        rvt[idx] = (dd < 9) ? f2bf_bits(relv[dd*K_DIM + col]) : (short)0;
    }
}

// ---------------------------------------------------------------------------
// Kernel 1: q/k/v projection. Block = (b, 16 t, d-half), 6 waves x 1 d-tile.
// Grid 1024 -> 4 blocks/CU (24 waves/CU). LDS stride padded to kill 16-way
// bank conflict on fragment reads.
// ---------------------------------------------------------------------------
__global__ __launch_bounds__(384)
void proj_kernel(const float* __restrict__ x, const float* __restrict__ cin,
                 const float* __restrict__ bk, const float* __restrict__ bv,
                 char* __restrict__ ws)
{
    __shared__ short xs[IT*XSTR];   // [t][c] bf16, padded stride
    __shared__ short cs[IT*XSTR];
    const int bid = blockIdx.x;
    const int b   = bid >> 8;
    const int rem = bid & 255;
    const int t0  = (rem >> 1) * IT;
    const int g   = rem & 1;
    const int tid = threadIdx.x;
    const int wave = tid >> 6, lane = tid & 63;
    const int q4 = lane >> 4, lr = lane & 15;

    for (int l = tid; l < 768; l += 384) {
        const int cr = l >> 2, u = l & 3;
        const size_t off = (size_t)(b*C_DIM + cr)*T_SEQ + t0 + 4*u;
        const float4 xv = *reinterpret_cast<const float4*>(x + off);
        const float4 cv = *reinterpret_cast<const float4*>(cin + off);
        xs[(4*u+0)*XSTR + cr] = f2bf_bits(xv.x);
        xs[(4*u+1)*XSTR + cr] = f2bf_bits(xv.y);
        xs[(4*u+2)*XSTR + cr] = f2bf_bits(xv.z);
        xs[(4*u+3)*XSTR + cr] = f2bf_bits(xv.w);
        cs[(4*u+0)*XSTR + cr] = f2bf_bits(cv.x);
        cs[(4*u+1)*XSTR + cr] = f2bf_bits(cv.y);
        cs[(4*u+2)*XSTR + cr] = f2bf_bits(cv.z);
        cs[(4*u+3)*XSTR + cr] = f2bf_bits(cv.w);
    }
    __syncthreads();

    const short* WqT = (const short*)(ws + OFF_WT(0));
    const short* WkT = (const short*)(ws + OFF_WT(1));
    const short* WvT = (const short*)(ws + OFF_WT(2));

    const int dt = g*6 + wave;    // this wave's d-tile (0..11)
    f32x4 qa = {0,0,0,0}, ka = {0,0,0,0}, va = {0,0,0,0};
    for (int kc = 0; kc < 6; ++kc) {
        const int ko = kc*32 + q4*8;
        const bf16x8 xf = *reinterpret_cast<const bf16x8*>(xs + lr*XSTR + ko);
        const bf16x8 cf = *reinterpret_cast<const bf16x8*>(cs + lr*XSTR + ko);
        const bf16x8 wqf = *reinterpret_cast<const bf16x8*>(WqT + (dt*16 + lr)*C_DIM + ko);
        const bf16x8 wkf = *reinterpret_cast<const bf16x8*>(WkT + (dt*16 + lr)*C_DIM + ko);
        const bf16x8 wvf = *reinterpret_cast<const bf16x8*>(WvT + (dt*16 + lr)*C_DIM + ko);
        qa = MFMA16(xf, wqf, qa, 0, 0, 0);   // m=t, n=d
        ka = MFMA16(cf, wkf, ka, 0, 0, 0);
        va = MFMA16(wvf, cf, va, 0, 0, 0);   // m=d, n=t
    }

    const float* bqs = (const float*)(ws + OFF_BQS);
    short* qbf = (short*)(ws + OFF_QBF);
    short* kbf = (short*)(ws + OFF_KBF);
    short* vtb = (short*)(ws + OFF_VTB);
    {   // q,k: col=d=dt*16+lr, row=t=q4*4+e
        const int d = dt*16 + lr, h = d/K_DIM, kk = d%K_DIM;
        const int bh = b*H_DIM + h;
        const float bq_v = bqs[d], bk_v = bk[d];
        #pragma unroll
        for (int e = 0; e < 4; ++e) {
            const int t = t0 + q4*4 + e;
            const size_t off = ((size_t)bh*T_SEQ + t)*K_DIM + kk;
            qbf[off] = f2bf_bits(qa[e] + bq_v);
            kbf[off] = f2bf_bits(ka[e] + bk_v);
        }
    }
    {   // v: col=t=lr, row=d=dt*16+q4*4+e
        #pragma unroll
        for (int e = 0; e < 4; ++e) {
            const int d = dt*16 + q4*4 + e, h = d/K_DIM, kk = d%K_DIM;
            const int bh = b*H_DIM + h;
            vtb[((size_t)bh*K_DIM + kk)*T_SEQ + t0 + lr] = f2bf_bits(va[e] + bv[d]);
        }
    }
}

// ---------------------------------------------------------------------------
// Kernel 2 (fused): banded attention + rel_v MFMA + output projection.
// Block = (b, 16 rows), 8 waves (0-3 head 0, 4-7 head 1).
// Softmax fully in registers (scores never round-trip LDS as fp32).
// ---------------------------------------------------------------------------
__global__ __launch_bounds__(512)
void attn_oproj_kernel(const int* __restrict__ mask, const float* __restrict__ bo,
                       float* __restrict__ y, char* __restrict__ ws)
{
    __shared__ __align__(16) short pb[2*HSH];   // 35328 B probs; later aliased as outs
    __shared__ float lt[257];                   // log1p table
    __shared__ float sm_m[2][4][16];            // per-head per-wave row maxima
    __shared__ float sm_s[2][4][16];            // per-head per-wave row sums
    __shared__ __align__(16) char upool[2560];  // pm(1088)+rl(1152) | pd(2560)
    unsigned* pm_s = (unsigned*)upool;          // [16][17]
    float*    rl   = (float*)(upool + 1088);    // [2][16][9]
    short*    pd_s = (short*)upool;             // [2][16][PDS]

    const short* qbf = (const short*)(ws + OFF_QBF);
    const short* kbf = (const short*)(ws + OFF_KBF);
    const short* vtb = (const short*)(ws + OFF_VTB);
    const short* rkb = (const short*)(ws + OFF_RELKBF);
    const short* rvt = (const short*)(ws + OFF_RVT);
    const short* WoT = (const short*)(ws + OFF_WT(3));

    const int b   = blockIdx.x >> 7;
    const int i0  = (blockIdx.x & 127) * IT;
    const int tid = threadIdx.x;
    const int wave = tid >> 6, lane = tid & 63;
    const int head = wave >> 2, wv = wave & 3;
    const int q4 = lane >> 4, lr = lane & 15;

    const int jlo  = max(0, i0 - BAND);
    const int jhi  = min(T_SEQ - 1, i0 + IT - 1 + BAND);
    const int wlen = jhi - jlo + 1;
    const size_t qk_base = (size_t)(b*H_DIM + head) * T_SEQ * K_DIM;

    for (int idx = tid; idx < 257; idx += 512) lt[idx] = log1pf((float)idx);

    // ---- in-block mask bit-pack
    if (tid < IT*PMW) {
        const int r = tid / PMW, w = tid % PMW;
        const int* mrow = mask + ((size_t)b*T_SEQ + i0 + r)*T_SEQ;
        unsigned bits = 0;
        #pragma unroll
        for (int g4 = 0; g4 < 8; ++g4) {
            const int jg = jlo + 32*w + 4*g4;
            if (jg + 3 < T_SEQ) {
                const int4 mv = *reinterpret_cast<const int4*>(mrow + jg);
                bits |= (unsigned)(mv.x != 0) << (4*g4);
                bits |= (unsigned)(mv.y != 0) << (4*g4+1);
                bits |= (unsigned)(mv.z != 0) << (4*g4+2);
                bits |= (unsigned)(mv.w != 0) << (4*g4+3);
            } else {
                #pragma unroll
                for (int e = 0; e < 4; ++e)
                    if (jg + e < T_SEQ && mrow[jg+e] != 0) bits |= 1u << (4*g4+e);
            }
        }
        pm_s[tid] = bits;
    }

    // ---- Q A-frags (own head)
    bf16x8 qa[3];
    {
        const short* qrow = qbf + qk_base + (size_t)(i0 + lr)*K_DIM + q4*8;
        #pragma unroll
        for (int kc = 0; kc < 3; ++kc)
            qa[kc] = *reinterpret_cast<const bf16x8*>(qrow + kc*32);
    }

    // ---- scores: kept in registers. s[u] tile jt = wv + 4u.
    // D layout: value (row i = i0+q4*4+e, col j = jt*16+lr) in s[u][e].
    f32x4 s[9];
    #pragma unroll
    for (int u = 0; u < 9; ++u) {
        s[u] = (f32x4){0.f,0.f,0.f,0.f};
        const int jt = wv + 4*u;
        if (jt < NJT) {
            int jr = jlo + jt*16 + lr;
            if (jr > T_SEQ-1) jr = T_SEQ-1;
            const short* krow = kbf + qk_base + (size_t)jr*K_DIM + q4*8;
            #pragma unroll
            for (int kc = 0; kc < 3; ++kc)
                s[u] = MFMA16(qa[kc], *reinterpret_cast<const bf16x8*>(krow + kc*32), s[u], 0, 0, 0);
        }
    }
    if (wv == 3) {                    // rl[r][dd] = q_r · relk_dd via MFMA
        const short* krow = rkb + lr*K_DIM + q4*8;
        f32x4 rs = {0.f,0.f,0.f,0.f};
        #pragma unroll
        for (int kc = 0; kc < 3; ++kc)
            rs = MFMA16(qa[kc], *reinterpret_cast<const bf16x8*>(krow + kc*32), rs, 0, 0, 0);
        if (lr < 9) {
            #pragma unroll
            for (int e = 0; e < 4; ++e)
                rl[head*144 + (q4*4 + e)*9 + lr] = rs[e];
        }
    }
    __syncthreads();   // B1: pm_s, lt, rl ready

    // ---- postprocess in registers: mask + proximal bias + rel-k, local max
    const int dbase = jlo - i0;       // dd = dbase + j - r
    float Mraw[4], Mc[4], Sl[4], c[4];
    #pragma unroll
    for (int e = 0; e < 4; ++e) Mraw[e] = -INFINITY;
    #pragma unroll
    for (int u = 0; u < 9; ++u) {
        const int jt = wv + 4*u;
        const int j = jt*16 + lr;
        const bool tv = (jt < NJT);
        #pragma unroll
        for (int e = 0; e < 4; ++e) {
            const int r = q4*4 + e;
            float val = -INFINITY;
            if (tv && j < wlen) {
                const int dd = dbase + j - r;
                const int ad = dd < 0 ? -dd : dd;
                const unsigned bit = (pm_s[r*PMW + (jt>>1)] >> (j & 31)) & 1u;
                if (ad <= BAND && bit) {
                    val = s[u][e] - lt[ad];
                    if ((unsigned)(dd + 4) <= 8u) val += rl[head*144 + r*9 + dd + 4];
                }
            }
            s[u][e] = val;
            Mraw[e] = fmaxf(Mraw[e], val);
        }
    }
    #pragma unroll
    for (int off = 8; off > 0; off >>= 1) {
        #pragma unroll
        for (int e = 0; e < 4; ++e)
            Mraw[e] = fmaxf(Mraw[e], __shfl_xor(Mraw[e], off, 64));
    }
    #pragma unroll
    for (int e = 0; e < 4; ++e) {
        Mc[e] = (Mraw[e] == -INFINITY) ? 0.f : Mraw[e];
        Sl[e] = 0.f;
    }
    #pragma unroll
    for (int u = 0; u < 9; ++u) {
        #pragma unroll
        for (int e = 0; e < 4; ++e) {
            const float p = __expf(s[u][e] - Mc[e]);
            s[u][e] = p;
            Sl[e] += p;
        }
    }
    #pragma unroll
    for (int off = 8; off > 0; off >>= 1) {
        #pragma unroll
        for (int e = 0; e < 4; ++e)
            Sl[e] += __shfl_xor(Sl[e], off, 64);
    }
    if (lr == 0) {
        #pragma unroll
        for (int e = 0; e < 4; ++e) {
            sm_m[head][wv][q4*4 + e] = Mraw[e];   // raw (-inf if empty)
            sm_s[head][wv][q4*4 + e] = Sl[e];
        }
    }
    __syncthreads();   // B2: partials ready

    #pragma unroll
    for (int e = 0; e < 4; ++e) {
        const int r = q4*4 + e;
        const float m0 = sm_m[head][0][r], m1 = sm_m[head][1][r];
        const float m2 = sm_m[head][2][r], m3 = sm_m[head][3][r];
        const float M = fmaxf(fmaxf(m0, m1), fmaxf(m2, m3));
        const float Mh = (M == -INFINITY) ? 0.f : M;
        const float S = sm_s[head][0][r]*__expf(((m0==-INFINITY)?0.f:m0) - Mh)
                      + sm_s[head][1][r]*__expf(((m1==-INFINITY)?0.f:m1) - Mh)
                      + sm_s[head][2][r]*__expf(((m2==-INFINITY)?0.f:m2) - Mh)
                      + sm_s[head][3][r]*__expf(((m3==-INFINITY)?0.f:m3) - Mh);
        const float inv = S > 0.f ? 1.f/S : 0.f;
        c[e] = __expf(Mc[e] - Mh) * inv;
    }
    // scale + write bf16 probs (pb[head][i][j])
    #pragma unroll
    for (int u = 0; u < 9; ++u) {
        const int jt = wv + 4*u;
        if (jt < NJT) {
            #pragma unroll
            for (int e = 0; e < 4; ++e)
                pb[head*HSH + (q4*4 + e)*PBS + jt*16 + lr] = f2bf_bits(s[u][e]*c[e]);
        }
    }
    __syncthreads();   // B3: pb ready (pm_s/rl dead)

    // ---- Pd fill (diagonal gather for rel_v MFMA); overlaps PV (both read pb)
    for (int idx = tid; idx < 2*IT*PDS; idx += 512) {
        const int hh = idx / (IT*PDS), rem2 = idx % (IT*PDS);
        const int r = rem2 / PDS, kk = rem2 % PDS;
        short v = 0;
        if (kk < 9) {
            const int jg = i0 + r + kk - 4;
            if (jg >= 0 && jg < T_SEQ)
                v = pb[hh*HSH + r*PBS + (jg - jlo)];
        }
        pd_s[idx] = v;
    }

    // ---- PV (4 waves per head split n-tiles 2/2/1/1)
    const short* pbh = pb + head*HSH;
    f32x4 o0 = {0.f,0.f,0.f,0.f}, o1 = {0.f,0.f,0.f,0.f};
    for (int kc = 0; kc < NJT/2; ++kc) {
        const bf16x8 pa = *reinterpret_cast<const bf16x8*>(pbh + lr*PBS + kc*32 + q4*8);
        int tc = jlo + kc*32 + q4*8;
        if (tc > T_SEQ-8) tc = T_SEQ-8;
        const bf16x8 vb0 = *reinterpret_cast<const bf16x8*>(
            vtb + qk_base + (size_t)(wv*16 + lr)*T_SEQ + tc);
        o0 = MFMA16(pa, vb0, o0, 0, 0, 0);
        if (wv < 2) {
            const bf16x8 vb1 = *reinterpret_cast<const bf16x8*>(
                vtb + qk_base + (size_t)((wv+4)*16 + lr)*T_SEQ + tc);
            o1 = MFMA16(pa, vb1, o1, 0, 0, 0);
        }
    }
    __syncthreads();   // B4: pd ready; pb dead -> reusable as outs

    // ---- rel_v contribution: one MFMA per n-tile
    {
        const bf16x8 pda = *reinterpret_cast<const bf16x8*>(pd_s + head*(IT*PDS) + lr*PDS + q4*8);
        const bf16x8 rv0 = *reinterpret_cast<const bf16x8*>(rvt + (wv*16 + lr)*32 + q4*8);
        o0 = MFMA16(pda, rv0, o0, 0, 0, 0);
        if (wv < 2) {
            const bf16x8 rv1 = *reinterpret_cast<const bf16x8*>(rvt + ((wv+4)*16 + lr)*32 + q4*8);
            o1 = MFMA16(pda, rv1, o1, 0, 0, 0);
        }
    }

    // ---- out tile -> LDS bf16 [16 t][192 d] (aliased over pb, stride OSTR)
    {
        short* outs = pb;
        #pragma unroll
        for (int u = 0; u < 2; ++u) {
            if (u == 1 && wv >= 2) break;
            const int nt = u ? wv + 4 : wv;
            const f32x4 oc = u ? o1 : o0;
            const int col = head*K_DIM + nt*16 + lr;
            #pragma unroll
            for (int e = 0; e < 4; ++e)
                outs[(q4*4 + e)*OSTR + col] = f2bf_bits(oc[e]);
        }
    }
    __syncthreads();   // B5: outs ready

    // ---- output projection: 12 d-tiles over 8 waves; y^T store (m=d, n=t)
    {
        const short* outs = pb;
        #pragma unroll
        for (int u = 0; u < 2; ++u) {
            if (u == 1 && wave >= 4) break;
            const int dt = u ? wave + 8 : wave;
            f32x4 a = {0.f,0.f,0.f,0.f};
            #pragma unroll
            for (int kc = 0; kc < 6; ++kc) {
                const int ko = kc*32 + q4*8;
                const bf16x8 af = *reinterpret_cast<const bf16x8*>(
                    WoT + (size_t)(dt*16 + lr)*C_DIM + ko);
                const bf16x8 bfr = *reinterpret_cast<const bf16x8*>(outs + lr*OSTR + ko);
                a = MFMA16(af, bfr, a, 0, 0, 0);
            }
            #pragma unroll
            for (int e = 0; e < 4; ++e) {
                const int d = dt*16 + q4*4 + e;
                y[((size_t)b*C_DIM + d)*T_SEQ + i0 + lr] = a[e] + bo[d];
            }
        }
    }
}

// ---------------------------------------------------------------------------
extern "C" void kernel_launch(void* const* d_in, const int* in_sizes, int n_in,
                              void* d_out, int out_size, void* d_ws, size_t ws_size,
                              hipStream_t stream)
{
    const float* x    = (const float*)d_in[0];
    const float* c    = (const float*)d_in[1];
    const float* Wq   = (const float*)d_in[2];
    const float* bq   = (const float*)d_in[3];
    const float* Wk   = (const float*)d_in[4];
    const float* bk   = (const float*)d_in[5];
    const float* Wv   = (const float*)d_in[6];
    const float* bv   = (const float*)d_in[7];
    const float* Wo   = (const float*)d_in[8];
    const float* bo   = (const float*)d_in[9];
    const float* relk = (const float*)d_in[10];
    const float* relv = (const float*)d_in[11];
    const int*   mask = (const int*)d_in[12];
    float*       y    = (float*)d_out;
    char*        ws   = (char*)d_ws;

    hipLaunchKernelGGL(prep_kernel, dim3(577), dim3(256), 0, stream,
                       Wq, Wk, Wv, Wo, bq, relk, relv, ws);
    hipLaunchKernelGGL(proj_kernel, dim3(B_DIM*(T_SEQ/16)*2), dim3(384), 0, stream,
                       x, c, bk, bv, ws);
    hipLaunchKernelGGL(attn_oproj_kernel, dim3(B_DIM*(T_SEQ/IT)), dim3(512), 0, stream,
                       mask, bo, y, ws);
}

// Round 3
// 175.332 us; speedup vs baseline: 1.0332x; 1.0332x over previous
//
#include <hip/hip_runtime.h>
#include <hip/hip_bf16.h>

#define B_DIM 4
#define C_DIM 192
#define T_SEQ 2048
#define H_DIM 2
#define K_DIM 96
#define BAND 256
#define IT 16            // q rows per attn block
#define NJT 34           // j-tiles of 16 in window (544 slots)
#define WSLOT 544        // padded window slots
#define WPD 556          // score row stride in dwords (16B aligned, ==12 mod 32)
#define PRS (2*WPD)      // prob row stride in shorts (same buffer, bf16 overlay)
#define PMW 17           // packed-mask words per row
#define XSTR 200         // proj LDS row stride in shorts (400B: breaks 16-way conflict)
#define OSTR 200         // out-tile row stride in shorts
#define PDS 40           // pd row stride in shorts

typedef __attribute__((ext_vector_type(8))) short bf16x8;
typedef __attribute__((ext_vector_type(4))) short bf16x4;
typedef __attribute__((ext_vector_type(4))) float f32x4;
#define MFMA16 __builtin_amdgcn_mfma_f32_16x16x32_bf16

__device__ __forceinline__ float bfbits2f(short s) {
    union { short s; __hip_bfloat16 h; } u; u.s = s; return __bfloat162float(u.h);
}
__device__ __forceinline__ short f2bf_bits(float f) {
    union { __hip_bfloat16 h; short s; } u; u.h = __float2bfloat16(f); return u.s;
}

// ---- workspace layout (bytes) ----
// WqT|WkT|WvT|WoT bf16 [192][192] (WqT prescaled); bqs fp32[192];
// relkbf bf16[16][96] (rows 9..15 zero); rvt bf16[96][32] (relv^T, cols 9..31 zero);
// qbf,kbf bf16 [bh][t][96]; vtb bf16 [bh][96][t]
#define OFF_WT(m)  ((size_t)(m)*73728)
#define OFF_BQS    ((size_t)294912)
#define OFF_RELKBF ((size_t)295680)
#define OFF_RVT    ((size_t)298752)
#define OFF_QBF    ((size_t)304896)
#define OFF_KBF    (OFF_QBF + 3145728)
#define OFF_VTB    (OFF_KBF + 3145728)

// XCD-chunked swizzle for 512-block grids: hw%8 -> XCD, give each XCD a
// contiguous 64-tile chunk so neighboring windows share one L2.
__device__ __forceinline__ int swz512(int hw) { return ((hw & 7) << 6) + (hw >> 3); }

// ---------------------------------------------------------------------------
// Prep: [0,576) weight transpose; 576: scaled bias + rel-k + relv^T tables.
// ---------------------------------------------------------------------------
__global__ __launch_bounds__(256)
void prep_kernel(const float* __restrict__ Wq, const float* __restrict__ Wk,
                 const float* __restrict__ Wv, const float* __restrict__ Wo,
                 const float* __restrict__ bq, const float* __restrict__ relk,
                 const float* __restrict__ relv, char* __restrict__ ws)
{
    const float qscale = 0.10206207261596577f;   // 1/sqrt(96)
    const int bidx = blockIdx.x;
    const int tid  = threadIdx.x;

    if (bidx < 576) {                       // ---- weight transpose
        const size_t idx = (size_t)bidx*256 + tid;
        const int mi  = (int)(idx / 36864);
        const int rem = (int)(idx % 36864);
        const int c = rem / C_DIM, d = rem % C_DIM;
        const float* src = (mi == 0) ? Wq : (mi == 1) ? Wk : (mi == 2) ? Wv : Wo;
        float v = src[c*C_DIM + d];
        if (mi == 0) v *= qscale;
        ((short*)(ws + OFF_WT(mi)))[d*C_DIM + c] = f2bf_bits(v);
        return;
    }
    if (tid < C_DIM)
        ((float*)(ws + OFF_BQS))[tid] = bq[tid]*qscale;
    short* rkb = (short*)(ws + OFF_RELKBF);
    for (int idx = tid; idx < 16*K_DIM; idx += 256) {
        const int row = idx / K_DIM;
        rkb[idx] = (row < 9) ? f2bf_bits(relk[idx]) : (short)0;
    }
    short* rvt = (short*)(ws + OFF_RVT);
    for (int idx = tid; idx < K_DIM*32; idx += 256) {
        const int col = idx >> 5, dd = idx & 31;
        rvt[idx] = (dd < 9) ? f2bf_bits(relv[dd*K_DIM + col]) : (short)0;
    }
}

// ---------------------------------------------------------------------------
// Kernel 1: q/k/v projection. Block = (b, 16 t), 4 waves x 3 d-tiles.
// XSTR pad kills the 16-way LDS conflict on x/c fragment reads.
// Swizzled to match attn's XCD mapping (writer XCD == reader XCD).
// ---------------------------------------------------------------------------
__global__ __launch_bounds__(256)
void proj_kernel(const float* __restrict__ x, const float* __restrict__ cin,
                 const float* __restrict__ bk, const float* __restrict__ bv,
                 char* __restrict__ ws)
{
    __shared__ short xs[IT*XSTR];   // [t][c] bf16, padded stride
    __shared__ short cs[IT*XSTR];
    const int bid = swz512(blockIdx.x);
    const int b   = bid >> 7;
    const int t0  = (bid & 127) * IT;
    const int tid = threadIdx.x;
    const int wave = tid >> 6, lane = tid & 63;
    const int q4 = lane >> 4, lr = lane & 15;

    for (int l = tid; l < 768; l += 256) {
        const int cr = l >> 2, u = l & 3;
        const size_t off = (size_t)(b*C_DIM + cr)*T_SEQ + t0 + 4*u;
        const float4 xv = *reinterpret_cast<const float4*>(x + off);
        const float4 cv = *reinterpret_cast<const float4*>(cin + off);
        xs[(4*u+0)*XSTR + cr] = f2bf_bits(xv.x);
        xs[(4*u+1)*XSTR + cr] = f2bf_bits(xv.y);
        xs[(4*u+2)*XSTR + cr] = f2bf_bits(xv.z);
        xs[(4*u+3)*XSTR + cr] = f2bf_bits(xv.w);
        cs[(4*u+0)*XSTR + cr] = f2bf_bits(cv.x);
        cs[(4*u+1)*XSTR + cr] = f2bf_bits(cv.y);
        cs[(4*u+2)*XSTR + cr] = f2bf_bits(cv.z);
        cs[(4*u+3)*XSTR + cr] = f2bf_bits(cv.w);
    }
    __syncthreads();

    const short* WqT = (const short*)(ws + OFF_WT(0));
    const short* WkT = (const short*)(ws + OFF_WT(1));
    const short* WvT = (const short*)(ws + OFF_WT(2));

    f32x4 qa[3], ka[3], va[3];
    #pragma unroll
    for (int j = 0; j < 3; ++j) {
        qa[j] = (f32x4){0,0,0,0}; ka[j] = (f32x4){0,0,0,0}; va[j] = (f32x4){0,0,0,0};
    }
    for (int kc = 0; kc < 6; ++kc) {
        const int ko = kc*32 + q4*8;
        const bf16x8 xf = *reinterpret_cast<const bf16x8*>(xs + lr*XSTR + ko);
        const bf16x8 cf = *reinterpret_cast<const bf16x8*>(cs + lr*XSTR + ko);
        #pragma unroll
        for (int j = 0; j < 3; ++j) {
            const int dt = 3*wave + j;
            const bf16x8 wqf = *reinterpret_cast<const bf16x8*>(WqT + (dt*16 + lr)*C_DIM + ko);
            const bf16x8 wkf = *reinterpret_cast<const bf16x8*>(WkT + (dt*16 + lr)*C_DIM + ko);
            const bf16x8 wvf = *reinterpret_cast<const bf16x8*>(WvT + (dt*16 + lr)*C_DIM + ko);
            qa[j] = MFMA16(xf, wqf, qa[j], 0, 0, 0);   // m=t, n=d
            ka[j] = MFMA16(cf, wkf, ka[j], 0, 0, 0);
            va[j] = MFMA16(wvf, cf, va[j], 0, 0, 0);   // m=d, n=t
        }
    }

    const float* bqs = (const float*)(ws + OFF_BQS);
    short* qbf = (short*)(ws + OFF_QBF);
    short* kbf = (short*)(ws + OFF_KBF);
    short* vtb = (short*)(ws + OFF_VTB);
    #pragma unroll
    for (int j = 0; j < 3; ++j) {
        const int dt = 3*wave + j;
        {   // q,k: col=d=dt*16+lr, row=t=q4*4+e
            const int d = dt*16 + lr, h = d/K_DIM, kk = d%K_DIM;
            const int bh = b*H_DIM + h;
            const float bq_v = bqs[d], bk_v = bk[d];
            #pragma unroll
            for (int e = 0; e < 4; ++e) {
                const int t = t0 + q4*4 + e;
                const size_t off = ((size_t)bh*T_SEQ + t)*K_DIM + kk;
                qbf[off] = f2bf_bits(qa[j][e] + bq_v);
                kbf[off] = f2bf_bits(ka[j][e] + bk_v);
            }
        }
        {   // v: col=t=lr, row=d=dt*16+q4*4+e
            #pragma unroll
            for (int e = 0; e < 4; ++e) {
                const int d = dt*16 + q4*4 + e, h = d/K_DIM, kk = d%K_DIM;
                const int bh = b*H_DIM + h;
                vtb[((size_t)bh*K_DIM + kk)*T_SEQ + t0 + lr] = f2bf_bits(va[e == e ? j : j][e] + bv[d]);
            }
        }
    }
}

// ---------------------------------------------------------------------------
// Kernel 2 (fused): banded attention (LDS softmax) + rel_v MFMA + output
// projection. Block = (b, 16 rows), 8 waves (0-3 head 0, 4-7 head 1).
// ---------------------------------------------------------------------------
__global__ __launch_bounds__(512, 4)
void attn_oproj_kernel(const int* __restrict__ mask, const float* __restrict__ bo,
                       float* __restrict__ y, char* __restrict__ ws)
{
    __shared__ __align__(16) float ps[2*IT*WPD]; // 71168 B scores -> bf16 probs -> outs
    __shared__ float lt[257];                    // log1p table
    __shared__ __align__(16) char upool[2560];   // pm(1088)+rl(1152) | pd(2560)
    unsigned* pm_s = (unsigned*)upool;           // [16][17]
    float*    rl   = (float*)(upool + 1088);     // [2][16][9]
    short*    pd_s = (short*)upool;              // [2][16][PDS]

    const short* qbf = (const short*)(ws + OFF_QBF);
    const short* kbf = (const short*)(ws + OFF_KBF);
    const short* vtb = (const short*)(ws + OFF_VTB);
    const short* rkb = (const short*)(ws + OFF_RELKBF);
    const short* rvt = (const short*)(ws + OFF_RVT);
    const short* WoT = (const short*)(ws + OFF_WT(3));

    const int bid = swz512(blockIdx.x);
    const int b   = bid >> 7;
    const int i0  = (bid & 127) * IT;
    const int tid = threadIdx.x;
    const int wave = tid >> 6, lane = tid & 63;
    const int head = wave >> 2, wv = wave & 3;
    const int q4 = lane >> 4, lr = lane & 15;

    const int jlo  = max(0, i0 - BAND);
    const int jhi  = min(T_SEQ - 1, i0 + IT - 1 + BAND);
    const int wlen = jhi - jlo + 1;
    const size_t qk_base = (size_t)(b*H_DIM + head) * T_SEQ * K_DIM;

    // ---- Q A-frags first (critical path of score phase)
    bf16x8 qa[3];
    {
        const short* qrow = qbf + qk_base + (size_t)(i0 + lr)*K_DIM + q4*8;
        #pragma unroll
        for (int kc = 0; kc < 3; ++kc)
            qa[kc] = *reinterpret_cast<const bf16x8*>(qrow + kc*32);
    }

    for (int idx = tid; idx < 257; idx += 512) lt[idx] = log1pf((float)idx);

    // ---- in-block mask bit-pack
    if (tid < IT*PMW) {
        const int r = tid / PMW, w = tid % PMW;
        const int* mrow = mask + ((size_t)b*T_SEQ + i0 + r)*T_SEQ;
        unsigned bits = 0;
        #pragma unroll
        for (int g4 = 0; g4 < 8; ++g4) {
            const int jg = jlo + 32*w + 4*g4;
            if (jg + 3 < T_SEQ) {
                const int4 mv = *reinterpret_cast<const int4*>(mrow + jg);
                bits |= (unsigned)(mv.x != 0) << (4*g4);
                bits |= (unsigned)(mv.y != 0) << (4*g4+1);
                bits |= (unsigned)(mv.z != 0) << (4*g4+2);
                bits |= (unsigned)(mv.w != 0) << (4*g4+3);
            } else {
                #pragma unroll
                for (int e = 0; e < 4; ++e)
                    if (jg + e < T_SEQ && mrow[jg+e] != 0) bits |= 1u << (4*g4+e);
            }
        }
        pm_s[tid] = bits;
    }

    // ---- scores (waves interleave j-tiles, 1-deep K prefetch)
    float* psh = ps + head*(IT*WPD);
    {
        int jt = wv;
        int jr = jlo + jt*16 + lr; if (jr > T_SEQ-1) jr = T_SEQ-1;
        const short* kr = kbf + qk_base + (size_t)jr*K_DIM + q4*8;
        bf16x8 kf0 = *reinterpret_cast<const bf16x8*>(kr);
        bf16x8 kf1 = *reinterpret_cast<const bf16x8*>(kr + 32);
        bf16x8 kf2 = *reinterpret_cast<const bf16x8*>(kr + 64);
        while (true) {
            const int jn = jt + 4;
            const bool more = (jn < NJT);
            bf16x8 nf0, nf1, nf2;
            if (more) {
                int jr2 = jlo + jn*16 + lr; if (jr2 > T_SEQ-1) jr2 = T_SEQ-1;
                const short* kr2 = kbf + qk_base + (size_t)jr2*K_DIM + q4*8;
                nf0 = *reinterpret_cast<const bf16x8*>(kr2);
                nf1 = *reinterpret_cast<const bf16x8*>(kr2 + 32);
                nf2 = *reinterpret_cast<const bf16x8*>(kr2 + 64);
            }
            f32x4 s = {0.f,0.f,0.f,0.f};
            s = MFMA16(qa[0], kf0, s, 0, 0, 0);
            s = MFMA16(qa[1], kf1, s, 0, 0, 0);
            s = MFMA16(qa[2], kf2, s, 0, 0, 0);
            float* pr = psh + (q4*4)*WPD + jt*16 + lr;
            pr[0*WPD] = s[0]; pr[1*WPD] = s[1]; pr[2*WPD] = s[2]; pr[3*WPD] = s[3];
            if (!more) break;
            kf0 = nf0; kf1 = nf1; kf2 = nf2;
            jt = jn;
        }
    }
    if (wv == 3) {                    // rl[r][dd] = q_r · relk_dd via MFMA
        const short* krow = rkb + lr*K_DIM + q4*8;
        f32x4 rs = {0.f,0.f,0.f,0.f};
        #pragma unroll
        for (int kc = 0; kc < 3; ++kc)
            rs = MFMA16(qa[kc], *reinterpret_cast<const bf16x8*>(krow + kc*32), rs, 0, 0, 0);
        if (lr < 9) {
            #pragma unroll
            for (int e = 0; e < 4; ++e)
                rl[head*144 + (q4*4 + e)*9 + lr] = rs[e];
        }
    }
    __syncthreads();   // B1: scores, pm_s, lt, rl ready

    // ---- postprocess + softmax (row rg by 16 lanes; 32 rows = 2 heads x 16)
    {
        const int rg = tid >> 4, sj = tid & 15;
        const int hh = rg >> 4, r = rg & 15;
        const int i = i0 + r;
        float* prow = ps + hh*(IT*WPD) + r*WPD;
        float vals[36];
        float m = -INFINITY;
        #pragma unroll
        for (int mm = 0; mm < 9; ++mm) {
            const int j0 = 4*sj + 64*mm;
            float4 pv = make_float4(0.f,0.f,0.f,0.f);
            unsigned mb = 0;
            if (j0 < WSLOT) {
                pv = *reinterpret_cast<const float4*>(prow + j0);
                mb = pm_s[r*PMW + (j0 >> 5)] >> (j0 & 31);
            }
            const float pe[4] = {pv.x, pv.y, pv.z, pv.w};
            #pragma unroll
            for (int e = 0; e < 4; ++e) {
                const int j = j0 + e;
                float val = -INFINITY;
                if (j0 < WSLOT && j < wlen) {
                    const int jg = jlo + j, dd = jg - i;
                    const int ad = dd < 0 ? -dd : dd;
                    if (ad <= BAND && ((mb >> e) & 1)) {
                        val = pe[e] - lt[ad];
                        if ((unsigned)(dd + 4) <= 8u) val += rl[hh*144 + r*9 + dd + 4];
                    }
                }
                vals[mm*4 + e] = val;
                m = fmaxf(m, val);
            }
        }
        #pragma unroll
        for (int off = 8; off > 0; off >>= 1) m = fmaxf(m, __shfl_xor(m, off, 64));
        if (m == -INFINITY) m = 0.f;
        float ssum = 0.f;
        #pragma unroll
        for (int u = 0; u < 36; ++u) { vals[u] = __expf(vals[u] - m); ssum += vals[u]; }
        #pragma unroll
        for (int off = 8; off > 0; off >>= 1) ssum += __shfl_xor(ssum, off, 64);
        const float inv = ssum > 0.f ? 1.f/ssum : 0.f;
        short* pbrow = (short*)prow;
        #pragma unroll
        for (int mm = 0; mm < 9; ++mm) {
            const int j0 = 4*sj + 64*mm;
            if (j0 < WSLOT) {
                bf16x4 w;
                #pragma unroll
                for (int e = 0; e < 4; ++e) w[e] = f2bf_bits(vals[mm*4+e]*inv);
                *reinterpret_cast<bf16x4*>(pbrow + j0) = w;
            }
        }
    }
    __syncthreads();   // B2: bf16 probs ready (pm_s/rl dead)

    // ---- Pd fill (diagonal gather for rel_v MFMA); overlaps PV (both read probs)
    for (int idx = tid; idx < 2*IT*PDS; idx += 512) {
        const int hh = idx / (IT*PDS), rem2 = idx % (IT*PDS);
        const int r = rem2 / PDS, kk = rem2 % PDS;
        short v = 0;
        if (kk < 9) {
            const int jg = i0 + r + kk - 4;
            if (jg >= 0 && jg < T_SEQ)
                v = ((const short*)ps)[hh*(IT*PRS) + r*PRS + (jg - jlo)];
        }
        pd_s[idx] = v;
    }

    // ---- PV (4 waves per head split n-tiles 2/2/1/1, 1-deep V prefetch)
    const short* pbh = (const short*)ps + head*(IT*PRS);
    f32x4 o0 = {0.f,0.f,0.f,0.f}, o1 = {0.f,0.f,0.f,0.f};
    {
        const short* vbase0 = vtb + qk_base + (size_t)(wv*16 + lr)*T_SEQ;
        const short* vbase1 = vtb + qk_base + (size_t)((wv+4)*16 + lr)*T_SEQ;
        int tc = jlo + q4*8; if (tc > T_SEQ-8) tc = T_SEQ-8;
        bf16x8 vb0 = *reinterpret_cast<const bf16x8*>(vbase0 + tc);
        bf16x8 vb1 = {};
        if (wv < 2) vb1 = *reinterpret_cast<const bf16x8*>(vbase1 + tc);
        for (int kc = 0; kc < NJT/2; ++kc) {
            bf16x8 nv0, nv1;
            const bool more = (kc + 1 < NJT/2);
            if (more) {
                int tn = jlo + (kc+1)*32 + q4*8; if (tn > T_SEQ-8) tn = T_SEQ-8;
                nv0 = *reinterpret_cast<const bf16x8*>(vbase0 + tn);
                if (wv < 2) nv1 = *reinterpret_cast<const bf16x8*>(vbase1 + tn);
            }
            const bf16x8 pa = *reinterpret_cast<const bf16x8*>(pbh + lr*PRS + kc*32 + q4*8);
            o0 = MFMA16(pa, vb0, o0, 0, 0, 0);
            if (wv < 2) o1 = MFMA16(pa, vb1, o1, 0, 0, 0);
            if (more) { vb0 = nv0; if (wv < 2) vb1 = nv1; }
        }
    }
    __syncthreads();   // B3: pd ready; prob buffer dead -> reusable as outs

    // ---- rel_v contribution: one MFMA per n-tile
    {
        const bf16x8 pda = *reinterpret_cast<const bf16x8*>(pd_s + head*(IT*PDS) + lr*PDS + q4*8);
        const bf16x8 rv0 = *reinterpret_cast<const bf16x8*>(rvt + (wv*16 + lr)*32 + q4*8);
        o0 = MFMA16(pda, rv0, o0, 0, 0, 0);
        if (wv < 2) {
            const bf16x8 rv1 = *reinterpret_cast<const bf16x8*>(rvt + ((wv+4)*16 + lr)*32 + q4*8);
            o1 = MFMA16(pda, rv1, o1, 0, 0, 0);
        }
    }

    // ---- out tile -> LDS bf16 [16 t][192 d] (aliased over ps, stride OSTR)
    {
        short* outs = (short*)ps;
        #pragma unroll
        for (int u = 0; u < 2; ++u) {
            if (u == 1 && wv >= 2) break;
            const int nt = u ? wv + 4 : wv;
            const f32x4 oc = u ? o1 : o0;
            const int col = head*K_DIM + nt*16 + lr;
            #pragma unroll
            for (int e = 0; e < 4; ++e)
                outs[(q4*4 + e)*OSTR + col] = f2bf_bits(oc[e]);
        }
    }
    __syncthreads();   // B4: outs ready

    // ---- output projection: 12 d-tiles over 8 waves; y^T store (m=d, n=t)
    {
        const short* outs = (const short*)ps;
        #pragma unroll
        for (int u = 0; u < 2; ++u) {
            if (u == 1 && wave >= 4) break;
            const int dt = u ? wave + 8 : wave;
            f32x4 a = {0.f,0.f,0.f,0.f};
            #pragma unroll
            for (int kc = 0; kc < 6; ++kc) {
                const int ko = kc*32 + q4*8;
                const bf16x8 af = *reinterpret_cast<const bf16x8*>(
                    WoT + (size_t)(dt*16 + lr)*C_DIM + ko);
                const bf16x8 bfr = *reinterpret_cast<const bf16x8*>(outs + lr*OSTR + ko);
                a = MFMA16(af, bfr, a, 0, 0, 0);
            }
            #pragma unroll
            for (int e = 0; e < 4; ++e) {
                const int d = dt*16 + q4*4 + e;
                y[((size_t)b*C_DIM + d)*T_SEQ + i0 + lr] = a[e] + bo[d];
            }
        }
    }
}

// ---------------------------------------------------------------------------
extern "C" void kernel_launch(void* const* d_in, const int* in_sizes, int n_in,
                              void* d_out, int out_size, void* d_ws, size_t ws_size,
                              hipStream_t stream)
{
    const float* x    = (const float*)d_in[0];
    const float* c    = (const float*)d_in[1];
    const float* Wq   = (const float*)d_in[2];
    const float* bq   = (const float*)d_in[3];
    const float* Wk   = (const float*)d_in[4];
    const float* bk   = (const float*)d_in[5];
    const float* Wv   = (const float*)d_in[6];
    const float* bv   = (const float*)d_in[7];
    const float* Wo   = (const float*)d_in[8];
    const float* bo   = (const float*)d_in[9];
    const float* relk = (const float*)d_in[10];
    const float* relv = (const float*)d_in[11];
    const int*   mask = (const int*)d_in[12];
    float*       y    = (float*)d_out;
    char*        ws   = (char*)d_ws;

    hipLaunchKernelGGL(prep_kernel, dim3(577), dim3(256), 0, stream,
                       Wq, Wk, Wv, Wo, bq, relk, relv, ws);
    hipLaunchKernelGGL(proj_kernel, dim3(B_DIM*(T_SEQ/16)), dim3(256), 0, stream,
                       x, c, bk, bv, ws);
    hipLaunchKernelGGL(attn_oproj_kernel, dim3(B_DIM*(T_SEQ/IT)), dim3(512), 0, stream,
                       mask, bo, y, ws);
}